// Round 3
// baseline (245.664 us; speedup 1.0000x reference)
//
#include <hip/hip_runtime.h>
#include <cstdint>
#include <cstddef>

// ---------------------------------------------------------------------------
// SelfAttnV2: x[4,2048,1024] fp32 -> QKV proj -> softmax(QK^T/32) V -> out proj
// bf16 MFMA GEMMs, fp32 accum. m201-style 256x256 8-phase template:
// 8 waves (2M x 4N, per-wave 128x64), BK=64, 2 LDS dbufs (128 KiB),
// block-quadrant phases, 1 half-tile stage/phase, counted vmcnt gates (T3+T4),
// LDS XOR swizzle (T2, 0 conflicts measured), setprio (T5), XCD swizzle (T1).
// ---------------------------------------------------------------------------

typedef __bf16 bf16;
typedef __bf16 bf16x8 __attribute__((ext_vector_type(8)));
typedef __bf16 bf16x4 __attribute__((ext_vector_type(4)));
typedef float  f32x4  __attribute__((ext_vector_type(4)));

#define THREADS 512
#define BM 256
#define BN 256
#define UNIT 8192   // one half-tile: 128 rows x 64 k bf16 = 16 KiB

__device__ __forceinline__ void gload_lds16(const bf16* g, bf16* l) {
  __builtin_amdgcn_global_load_lds(
      (const __attribute__((address_space(1))) unsigned int*)g,
      (__attribute__((address_space(3))) unsigned int*)l, 16, 0, 0);
}

// Stage one 128x64 unit; chunk c holds global (row=c>>3, slot=(c&7)^(row&7)).
__device__ __forceinline__ void stage_unit(const bf16* g0, long ld, bf16* ldsu, int tid) {
  const int wv = tid >> 6;
  #pragma unroll
  for (int j = 0; j < 2; ++j) {
    const int c = j * 512 + tid;
    const int r = c >> 3;
    const int sg = (c & 7) ^ (r & 7);
    const int cb = j * 512 + (wv << 6);   // wave-uniform chunk base
    gload_lds16(g0 + (long)r * ld + sg * 8, ldsu + (size_t)cb * 8);
  }
}

__device__ __forceinline__ bf16x8 rd_frag(const bf16* unitb, int r, int s) {
  return *(const bf16x8*)(unitb + (size_t)r * 64 + (size_t)((s ^ (r & 7)) * 8));
}

#define GATE(N)  asm volatile("s_waitcnt vmcnt(" #N ")" ::: "memory")
#define LGKM0()  asm volatile("s_waitcnt lgkmcnt(0)" ::: "memory")
#define SBAR()   __builtin_amdgcn_s_barrier()
#define SCHED0() __builtin_amdgcn_sched_barrier(0)

// One phase = block quadrant (MH,NH) of K-tile in dbuf DB.
// [reads][stage] bar; lgkm0; 16 MFMA; [end-gate] bar.
#define PHASE(DB, MH, NH, RA, RB, STAGE_CODE, GATE_CODE)                         \
  {                                                                              \
    if (RA) {                                                                    \
      _Pragma("unroll") for (int mf = 0; mf < 4; ++mf)                           \
        _Pragma("unroll") for (int ks = 0; ks < 2; ++ks)                         \
          aF[mf][ks] = rd_frag(&lds[DB][MH][0], wsm * 64 + mf * 16 + lr, ks * 4 + lh); \
    }                                                                            \
    if (RB) {                                                                    \
      _Pragma("unroll") for (int nf = 0; nf < 2; ++nf)                           \
        _Pragma("unroll") for (int ks = 0; ks < 2; ++ks)                         \
          bF[NH][nf][ks] = rd_frag(&lds[DB][2 + NH][0], wsn * 32 + nf * 16 + lr, ks * 4 + lh); \
    }                                                                            \
    STAGE_CODE;                                                                  \
    SBAR();                                                                      \
    LGKM0();                                                                     \
    SCHED0();                                                                    \
    __builtin_amdgcn_s_setprio(1);                                               \
    _Pragma("unroll") for (int mf = 0; mf < 4; ++mf)                             \
      _Pragma("unroll") for (int nf = 0; nf < 2; ++nf)                           \
        _Pragma("unroll") for (int ks = 0; ks < 2; ++ks)                         \
          acc[(MH)*4 + mf][(NH)*2 + nf] = __builtin_amdgcn_mfma_f32_16x16x32_bf16( \
              aF[mf][ks], bF[NH][nf][ks], acc[(MH)*4 + mf][(NH)*2 + nf], 0, 0, 0); \
    __builtin_amdgcn_s_setprio(0);                                               \
    GATE_CODE;                                                                   \
    SBAR();                                                                      \
    SCHED0();                                                                    \
  }

// ---------------------------------------------------------------------------
// MODE 0: QKV (+bias -> Q|K|V row-major)  MODE 1: scores (*scale)
// MODE 2: PV -> bf16                      MODE 3: out proj (+bias) fp32
// ---------------------------------------------------------------------------
template <int MODE>
__device__ __forceinline__ void gemm_body(
    const bf16* __restrict__ A, long sAz, int lda,
    const bf16* __restrict__ B, long sBz, int ldb, int K,
    bf16* __restrict__ p0, long sCz, bf16* __restrict__ p1, bf16* __restrict__ p2,
    float* __restrict__ fout, const float* __restrict__ bias, float scale) {
  __shared__ bf16 lds[2][4][UNIT];   // [dbuf][A0,A1,B0->2,B1->3][unit] = 128 KiB
  const int tid = threadIdx.x;
  const int wv = tid >> 6, ln = tid & 63;
  const int wsm = wv >> 2, wsn = wv & 3;     // 2M x 4N wave grid; wave tile 128x64
  const int lr = ln & 15, lh = ln >> 4;

  // T1: XCD-aware swizzle (all grids are %8 == 0 -> bijective)
  const int gx = gridDim.x, gy = gridDim.y;
  const int lin = blockIdx.x + gx * (blockIdx.y + gy * blockIdx.z);
  const int nwg = gx * gy * gridDim.z;
  const int swz = (lin & 7) * (nwg >> 3) + (lin >> 3);
  const int bx = swz % gx;
  const int tq = swz / gx;
  const int by = tq % gy;
  const int z  = tq / gy;

  const int m0 = bx * BM, n0 = by * BN;
  const bf16* Ag = A + (long)z * sAz + (long)m0 * lda;
  const bf16* Bg = B + (long)z * sBz + (long)n0 * ldb;
  const int NITER = K / 128;   // 2 K-tiles (of 64) per iter

  // prologue: tile0 -> D0 (A0,B0,A1,B1), tile1 -> D1 (A0,B0)  [= s3..s8 order]
  stage_unit(Ag,             lda, &lds[0][0][0], tid);
  stage_unit(Bg,             ldb, &lds[0][2][0], tid);
  stage_unit(Ag + 128 * lda, lda, &lds[0][1][0], tid);
  stage_unit(Bg + 128 * ldb, ldb, &lds[0][3][0], tid);
  stage_unit(Ag + 64,        lda, &lds[1][0][0], tid);
  stage_unit(Bg + 64,        ldb, &lds[1][2][0], tid);
  GATE(8);     // forces D0.A0,B0 complete (all waves, via barrier below)
  SBAR();
  SCHED0();

  f32x4 acc[8][4];
  #pragma unroll
  for (int i = 0; i < 8; ++i)
    #pragma unroll
    for (int j = 0; j < 4; ++j) acc[i][j] = f32x4{0.f, 0.f, 0.f, 0.f};
  bf16x8 aF[4][2], bF[2][2][2];

  for (int it = 0; it < NITER; ++it) {
    const bool nl = (it + 1 < NITER);
    const long ktA = 2L * it + 1, ktB = 2L * it + 2, ktC = 2L * it + 3;
    // p1: D0 (0,0); stage D1.A1 <- tile ktA (its old data last read prev p7)
    PHASE(0, 0, 0, 1, 1,
      { stage_unit(Ag + 128 * lda + ktA * 64, lda, &lds[1][1][0], tid); },
      { GATE(6); });
    // p2: D0 (0,1); stage D1.B1 <- ktA
    PHASE(0, 0, 1, 0, 1,
      { stage_unit(Bg + 128 * ldb + ktA * 64, ldb, &lds[1][3][0], tid); },
      { GATE(10); });
    // p3: D0 (1,0); stage D0.A0 <- ktB
    PHASE(0, 1, 0, 1, 0,
      { if (nl) stage_unit(Ag + ktB * 64, lda, &lds[0][0][0], tid); },
      {});
    // p4: D0 (1,1); stage D0.B0 <- ktB
    PHASE(0, 1, 1, 0, 0,
      { if (nl) stage_unit(Bg + ktB * 64, ldb, &lds[0][2][0], tid); },
      { if (nl) { GATE(8); } else { GATE(4); } });
    // p5: D1 (0,0); stage D0.A1 <- ktB
    PHASE(1, 0, 0, 1, 1,
      { if (nl) stage_unit(Ag + 128 * lda + ktB * 64, lda, &lds[0][1][0], tid); },
      { if (nl) { GATE(6); } else { GATE(0); } });
    // p6: D1 (0,1); stage D0.B1 <- ktB
    PHASE(1, 0, 1, 0, 1,
      { if (nl) stage_unit(Bg + 128 * ldb + ktB * 64, ldb, &lds[0][3][0], tid); },
      { GATE(10); });
    // p7: D1 (1,0); stage D1.A0 <- ktC
    PHASE(1, 1, 0, 1, 0,
      { if (nl) stage_unit(Ag + ktC * 64, lda, &lds[1][0][0], tid); },
      {});
    // p8: D1 (1,1); stage D1.B0 <- ktC
    PHASE(1, 1, 1, 0, 0,
      { if (nl) stage_unit(Bg + ktC * 64, ldb, &lds[1][2][0], tid); },
      { GATE(8); });
  }

  // epilogue: C/D layout col=lane&15, row=(lane>>4)*4+reg
  #pragma unroll
  for (int mi = 0; mi < 8; ++mi) {
    #pragma unroll
    for (int ni = 0; ni < 4; ++ni) {
      #pragma unroll
      for (int rg = 0; rg < 4; ++rg) {
        const int gm = m0 + (mi >> 2) * 128 + wsm * 64 + (mi & 3) * 16 + lh * 4 + rg;
        const int gn = n0 + (ni >> 1) * 128 + wsn * 32 + (ni & 1) * 16 + lr;
        float v = acc[mi][ni][rg];
        if constexpr (MODE == 0) {
          v += bias[gn];
          if (gn < 1024)       p0[(size_t)gm * 1024 + gn] = (bf16)v;
          else if (gn < 2048)  p1[(size_t)gm * 1024 + (gn - 1024)] = (bf16)v;
          else                 p2[(size_t)gm * 1024 + (gn - 2048)] = (bf16)v;
        } else if constexpr (MODE == 1) {
          p0[(size_t)z * sCz + (size_t)gm * 2048 + gn] = (bf16)(v * scale);
        } else if constexpr (MODE == 2) {
          p0[(size_t)z * sCz + (size_t)gm * 1024 + gn] = (bf16)v;
        } else {
          fout[(size_t)gm * 1024 + gn] = v + bias[gn];
        }
      }
    }
  }
}

#define GEMM_ARGS const bf16* A, long sAz, int lda, const bf16* B, long sBz, int ldb, \
                  int K, bf16* p0, long sCz, bf16* p1, bf16* p2, float* fout,         \
                  const float* bias, float scale
__global__ __launch_bounds__(THREADS, 2) void gemm_qkv(GEMM_ARGS) {
  gemm_body<0>(A, sAz, lda, B, sBz, ldb, K, p0, sCz, p1, p2, fout, bias, scale);
}
__global__ __launch_bounds__(THREADS, 2) void gemm_sc(GEMM_ARGS) {
  gemm_body<1>(A, sAz, lda, B, sBz, ldb, K, p0, sCz, p1, p2, fout, bias, scale);
}
__global__ __launch_bounds__(THREADS, 2) void gemm_pv(GEMM_ARGS) {
  gemm_body<2>(A, sAz, lda, B, sBz, ldb, K, p0, sCz, p1, p2, fout, bias, scale);
}
__global__ __launch_bounds__(THREADS, 2) void gemm_out(GEMM_ARGS) {
  gemm_body<3>(A, sAz, lda, B, sBz, ldb, K, p0, sCz, p1, p2, fout, bias, scale);
}

// ---------------------------------------------------------------------------
__global__ __launch_bounds__(256) void k_f32_to_bf16(const float* __restrict__ in,
                                                     bf16* __restrict__ out, long n) {
  long i = ((long)blockIdx.x * blockDim.x + threadIdx.x) * 4;
  if (i + 3 < n) {
    float4 v = *(const float4*)(in + i);
    bf16x4 o;
    o[0] = (bf16)v.x; o[1] = (bf16)v.y; o[2] = (bf16)v.z; o[3] = (bf16)v.w;
    *(bf16x4*)(out + i) = o;
  }
}

__global__ __launch_bounds__(256) void k_transpose(const float* __restrict__ in,
                                                   bf16* __restrict__ out, int R, int C) {
  __shared__ float t[32][33];
  int c0 = blockIdx.x * 32, r0 = blockIdx.y * 32;
  int tx = threadIdx.x, ty = threadIdx.y;
  #pragma unroll
  for (int dy = 0; dy < 32; dy += 8)
    t[ty + dy][tx] = in[(size_t)(r0 + ty + dy) * C + c0 + tx];
  __syncthreads();
  #pragma unroll
  for (int dy = 0; dy < 32; dy += 8)
    out[(size_t)(c0 + ty + dy) * R + r0 + tx] = (bf16)t[tx][ty + dy];
}

__global__ __launch_bounds__(256) void k_transpose_v(const bf16* __restrict__ in,
                                                     bf16* __restrict__ out) {
  __shared__ bf16 t[32][33];
  const int z = blockIdx.z;
  in  += (size_t)z * 2048 * 1024;
  out += (size_t)z * 1024 * 2048;
  int h0 = blockIdx.x * 32, s0 = blockIdx.y * 32;
  int tx = threadIdx.x, ty = threadIdx.y;
  #pragma unroll
  for (int dy = 0; dy < 32; dy += 8)
    t[ty + dy][tx] = in[(size_t)(s0 + ty + dy) * 1024 + h0 + tx];
  __syncthreads();
  #pragma unroll
  for (int dy = 0; dy < 32; dy += 8)
    out[(size_t)(h0 + ty + dy) * 2048 + s0 + tx] = t[tx][ty + dy];
}

__global__ __launch_bounds__(256) void k_softmax(bf16* __restrict__ S) {
  const int row = blockIdx.x;
  bf16* p = S + (size_t)row * 2048;
  const int tid = threadIdx.x;
  bf16x8 vin = *(const bf16x8*)(p + tid * 8);
  float x[8];
  float mx = -1e30f;
  #pragma unroll
  for (int i = 0; i < 8; ++i) { x[i] = (float)vin[i]; mx = fmaxf(mx, x[i]); }
  #pragma unroll
  for (int off = 32; off; off >>= 1) mx = fmaxf(mx, __shfl_down(mx, off));
  __shared__ float redm[4];
  if ((tid & 63) == 0) redm[tid >> 6] = mx;
  __syncthreads();
  mx = fmaxf(fmaxf(redm[0], redm[1]), fmaxf(redm[2], redm[3]));
  float s = 0.f;
  #pragma unroll
  for (int i = 0; i < 8; ++i) { x[i] = __expf(x[i] - mx); s += x[i]; }
  #pragma unroll
  for (int off = 32; off; off >>= 1) s += __shfl_down(s, off);
  __shared__ float reds[4];
  if ((tid & 63) == 0) reds[tid >> 6] = s;
  __syncthreads();
  s = reds[0] + reds[1] + reds[2] + reds[3];
  float inv = 1.0f / s;
  bf16x8 vo;
  #pragma unroll
  for (int i = 0; i < 8; ++i) vo[i] = (bf16)(x[i] * inv);
  *(bf16x8*)(p + tid * 8) = vo;
}

// ---------------------------------------------------------------------------
extern "C" void kernel_launch(void* const* d_in, const int* in_sizes, int n_in,
                              void* d_out, int out_size, void* d_ws, size_t ws_size,
                              hipStream_t stream) {
  const float* x    = (const float*)d_in[0];
  const float* Wqkv = (const float*)d_in[1];
  const float* bqkv = (const float*)d_in[2];
  const float* Wout = (const float*)d_in[3];
  const float* bout = (const float*)d_in[4];
  float* out = (float*)d_out;

  char* w = (char*)d_ws;
  const size_t MB = 1ull << 20;
  bf16* Xb  = (bf16*)(w);             // 16MB; dead after QKV -> reused as VT
  bf16* WqT = (bf16*)(w + 16 * MB);   //  6MB
  bf16* WoT = (bf16*)(w + 22 * MB);   //  2MB
  bf16* Qb  = (bf16*)(w + 24 * MB);   // 16MB
  bf16* Kb  = (bf16*)(w + 40 * MB);   // 16MB
  bf16* Vb  = (bf16*)(w + 56 * MB);   // 16MB
  bf16* Sb  = (bf16*)(w + 72 * MB);   // 32MB (S -> P in place)
  bf16* AO  = (bf16*)(w + 104 * MB);  // 16MB  (total 120MB)
  bf16* VT  = Xb;

  k_f32_to_bf16<<<8192, 256, 0, stream>>>(x, Xb, 8388608L);
  dim3 tb(32, 8);
  k_transpose<<<dim3(96, 32), tb, 0, stream>>>(Wqkv, WqT, 1024, 3072);
  k_transpose<<<dim3(32, 32), tb, 0, stream>>>(Wout, WoT, 1024, 1024);

  // QKV: [8192,1024] x W^T[3072,1024] + bias -> Q,K,V   (384 blocks)
  gemm_qkv<<<dim3(32, 12), THREADS, 0, stream>>>(
      Xb, 0L, 1024, WqT, 0L, 1024, 1024, Qb, 0L, Kb, Vb, nullptr, bqkv, 1.0f);

  k_transpose_v<<<dim3(32, 64, 4), tb, 0, stream>>>(Vb, VT);

  // scores: per batch Q x K^T * 1/32    (256 blocks)
  gemm_sc<<<dim3(8, 8, 4), THREADS, 0, stream>>>(
      Qb, 2048L * 1024, 1024, Kb, 2048L * 1024, 1024, 1024,
      Sb, 2048L * 2048, nullptr, nullptr, nullptr, nullptr, 0.03125f);

  k_softmax<<<8192, 256, 0, stream>>>(Sb);

  // PV: per batch P[2048,2048] x VT[1024,2048](B^T) -> AO   (128 blocks)
  gemm_pv<<<dim3(8, 4, 4), THREADS, 0, stream>>>(
      Sb, 2048L * 2048, 2048, VT, 1024L * 2048, 2048, 2048,
      AO, 2048L * 1024, nullptr, nullptr, nullptr, nullptr, 1.0f);

  // out proj + bias -> fp32   (128 blocks)
  gemm_out<<<dim3(32, 4), THREADS, 0, stream>>>(
      AO, 0L, 1024, WoT, 0L, 1024, 1024,
      nullptr, 0L, nullptr, nullptr, out, bout, 1.0f);
}

// Round 4
// 217.392 us; speedup vs baseline: 1.1301x; 1.1301x over previous
//
#include <hip/hip_runtime.h>
#include <cstdint>
#include <cstddef>

// ---------------------------------------------------------------------------
// SelfAttnV2: x[4,2048,1024] fp32 -> QKV proj -> softmax(QK^T/32) V -> out proj
// bf16 MFMA GEMMs, fp32 accum.
//  - QKV / PV / OUT: 256x128 2-phase 3-buffer-ring kernel (R2 structure,
//    full-round grids 768/256/256, measured 693 TF-class).
//  - SC: 256x256 8-phase template (m201-style) with z-grouped XCD swizzle
//    (by-fastest decode) -> grid 256 = exactly 1 round, LDS-BW ceiling 61%.
// ---------------------------------------------------------------------------

typedef __bf16 bf16;
typedef __bf16 bf16x8 __attribute__((ext_vector_type(8)));
typedef __bf16 bf16x4 __attribute__((ext_vector_type(4)));
typedef float  f32x4  __attribute__((ext_vector_type(4)));

#define THREADS 512
#define UNIT 8192   // staging unit: 128 rows x 64 k bf16 = 16 KiB

__device__ __forceinline__ void gload_lds16(const bf16* g, bf16* l) {
  __builtin_amdgcn_global_load_lds(
      (const __attribute__((address_space(1))) unsigned int*)g,
      (__attribute__((address_space(3))) unsigned int*)l, 16, 0, 0);
}

// Stage one 128x64 unit; chunk c holds global (row=c>>3, slot=(c&7)^(row&7)).
__device__ __forceinline__ void stage_unit(const bf16* g0, long ld, bf16* ldsu, int tid) {
  const int wv = tid >> 6;
  #pragma unroll
  for (int j = 0; j < 2; ++j) {
    const int c = j * 512 + tid;
    const int r = c >> 3;
    const int sg = (c & 7) ^ (r & 7);
    const int cb = j * 512 + (wv << 6);   // wave-uniform chunk base
    gload_lds16(g0 + (long)r * ld + sg * 8, ldsu + (size_t)cb * 8);
  }
}

__device__ __forceinline__ bf16x8 rd_frag(const bf16* unitb, int r, int s) {
  return *(const bf16x8*)(unitb + (size_t)r * 64 + (size_t)((s ^ (r & 7)) * 8));
}

#define GATE(N)  asm volatile("s_waitcnt vmcnt(" #N ")" ::: "memory")
#define LGKM0()  asm volatile("s_waitcnt lgkmcnt(0)" ::: "memory")
#define SBAR()   __builtin_amdgcn_s_barrier()
#define SCHED0() __builtin_amdgcn_sched_barrier(0)

// ===========================================================================
// Kernel A: 256x128 2-phase, 3-buffer ring (QKV / PV / OUT).
// 8 waves as 4M x 2N, wave tile 64x64.
// ===========================================================================
#define BM2 256
#define BN2 128
#define BK2 64
#define BUFELS (3*UNIT)

template <int MODE>
__device__ __forceinline__ void gemm2_body(
    const bf16* __restrict__ A, long sAz, int lda,
    const bf16* __restrict__ B, long sBz, int ldb, int K,
    bf16* __restrict__ p0, long sCz, bf16* __restrict__ p1, bf16* __restrict__ p2,
    float* __restrict__ fout, const float* __restrict__ bias, float scale) {
  __shared__ bf16 lds[3 * BUFELS];   // 144 KiB
  const int tid = threadIdx.x;
  const int wv = tid >> 6, ln = tid & 63;
  const int wr = wv >> 1, wc = wv & 1;        // 4(M) x 2(N), 64x64 each
  const int lr = ln & 15, lh = ln >> 4;
  const int m0 = blockIdx.x * BM2, n0 = blockIdx.y * BN2;
  const int z = blockIdx.z;
  A += (long)z * sAz;
  B += (long)z * sBz;
  const bf16* Ag = A + (long)m0 * lda;
  const bf16* Bg = B + (long)n0 * ldb;
  const int NT = K / BK2;

  #pragma unroll
  for (int t = 0; t < 2; ++t) {
    bf16* bb = lds + t * BUFELS;
    stage_unit(Ag + t * BK2, lda, bb, tid);
    stage_unit(Ag + (long)128 * lda + t * BK2, lda, bb + UNIT, tid);
    stage_unit(Bg + t * BK2, ldb, bb + 2 * UNIT, tid);
  }
  GATE(6);
  SCHED0();
  SBAR();

  f32x4 acc[4][4];
  #pragma unroll
  for (int i = 0; i < 4; ++i)
    #pragma unroll
    for (int j = 0; j < 4; ++j)
      acc[i][j] = f32x4{0.f, 0.f, 0.f, 0.f};

  const int aru = (wr & 1) * 64;   // A row base within unit
  const int au  = wr >> 1;         // which A unit

  int buf = 0, nb = 2;
  for (int t = 0; t < NT; ++t) {
    const bf16* Au = lds + buf * BUFELS + au * UNIT;
    const bf16* Bu = lds + buf * BUFELS + 2 * UNIT;
    bf16* Pn = lds + nb * BUFELS;
    const bool pf = (t + 2 < NT);
    bf16x8 aF[2][2], bF[4][2];

    // ---- phase 1 (m-frags 0,1) ----
    #pragma unroll
    for (int i = 0; i < 2; ++i)
      #pragma unroll
      for (int ks = 0; ks < 2; ++ks)
        aF[i][ks] = rd_frag(Au, aru + i * 16 + lr, (ks << 2) + lh);
    #pragma unroll
    for (int nf = 0; nf < 4; ++nf)
      #pragma unroll
      for (int ks = 0; ks < 2; ++ks)
        bF[nf][ks] = rd_frag(Bu, wc * 64 + nf * 16 + lr, (ks << 2) + lh);
    if (pf) {
      stage_unit(Ag + (long)(t + 2) * BK2, lda, Pn, tid);
      stage_unit(Ag + (long)128 * lda + (long)(t + 2) * BK2, lda, Pn + UNIT, tid);
    }
    SBAR();
    LGKM0();
    SCHED0();
    __builtin_amdgcn_s_setprio(1);
    #pragma unroll
    for (int i = 0; i < 2; ++i)
      #pragma unroll
      for (int nf = 0; nf < 4; ++nf)
        #pragma unroll
        for (int ks = 0; ks < 2; ++ks)
          acc[i][nf] = __builtin_amdgcn_mfma_f32_16x16x32_bf16(aF[i][ks], bF[nf][ks], acc[i][nf], 0, 0, 0);
    __builtin_amdgcn_s_setprio(0);
    SBAR();

    // ---- phase 2 (m-frags 2,3) ----
    #pragma unroll
    for (int i = 0; i < 2; ++i)
      #pragma unroll
      for (int ks = 0; ks < 2; ++ks)
        aF[i][ks] = rd_frag(Au, aru + 32 + i * 16 + lr, (ks << 2) + lh);
    if (pf) stage_unit(Bg + (long)(t + 2) * BK2, ldb, Pn + 2 * UNIT, tid);
    SBAR();
    LGKM0();
    SCHED0();
    __builtin_amdgcn_s_setprio(1);
    #pragma unroll
    for (int i = 0; i < 2; ++i)
      #pragma unroll
      for (int nf = 0; nf < 4; ++nf)
        #pragma unroll
        for (int ks = 0; ks < 2; ++ks)
          acc[2 + i][nf] = __builtin_amdgcn_mfma_f32_16x16x32_bf16(aF[i][ks], bF[nf][ks], acc[2 + i][nf], 0, 0, 0);
    __builtin_amdgcn_s_setprio(0);
    if (t + 1 < NT) {
      if (pf) { GATE(6); } else { GATE(0); }
      SCHED0();
    }
    SBAR();

    buf = (buf == 2) ? 0 : buf + 1;
    nb  = (nb == 2) ? 0 : nb + 1;
  }

  // epilogue: C/D layout col=lane&15, row=(lane>>4)*4+reg
  #pragma unroll
  for (int mf = 0; mf < 4; ++mf) {
    #pragma unroll
    for (int nf = 0; nf < 4; ++nf) {
      #pragma unroll
      for (int rg = 0; rg < 4; ++rg) {
        const int gm = m0 + wr * 64 + mf * 16 + lh * 4 + rg;
        const int gn = n0 + wc * 64 + nf * 16 + lr;
        float v = acc[mf][nf][rg];
        if constexpr (MODE == 0) {
          v += bias[gn];
          if (gn < 1024)       p0[(size_t)gm * 1024 + gn] = (bf16)v;          // Q
          else if (gn < 2048)  p1[(size_t)gm * 1024 + (gn - 1024)] = (bf16)v; // K
          else                 p2[(size_t)gm * 1024 + (gn - 2048)] = (bf16)v; // V
        } else if constexpr (MODE == 2) {
          p0[(size_t)z * sCz + (size_t)gm * 1024 + gn] = (bf16)v;
        } else {
          fout[(size_t)gm * 1024 + gn] = v + bias[gn];
        }
      }
    }
  }
}

#define GEMM_ARGS const bf16* A, long sAz, int lda, const bf16* B, long sBz, int ldb, \
                  int K, bf16* p0, long sCz, bf16* p1, bf16* p2, float* fout,         \
                  const float* bias, float scale
__global__ __launch_bounds__(THREADS, 2) void gemm_qkv(GEMM_ARGS) {
  gemm2_body<0>(A, sAz, lda, B, sBz, ldb, K, p0, sCz, p1, p2, fout, bias, scale);
}
__global__ __launch_bounds__(THREADS, 2) void gemm_pv(GEMM_ARGS) {
  gemm2_body<2>(A, sAz, lda, B, sBz, ldb, K, p0, sCz, p1, p2, fout, bias, scale);
}
__global__ __launch_bounds__(THREADS, 2) void gemm_out(GEMM_ARGS) {
  gemm2_body<3>(A, sAz, lda, B, sBz, ldb, K, p0, sCz, p1, p2, fout, bias, scale);
}

// ===========================================================================
// Kernel B: 256x256 8-phase (SC only). 8 waves 2M x 4N, wave tile 128x64.
// XCD swizzle: chunk-contiguous with by FASTEST (z slow, bx mid) so each XCD
// keeps a small A-panel set resident and streams only its z's B.
// ===========================================================================
#define BM8 256
#define BN8 256

#define PHASE(DB, MH, NH, RA, RB, STAGE_CODE, GATE_CODE)                         \
  {                                                                              \
    if (RA) {                                                                    \
      _Pragma("unroll") for (int mf = 0; mf < 4; ++mf)                           \
        _Pragma("unroll") for (int ks = 0; ks < 2; ++ks)                         \
          aF[mf][ks] = rd_frag(&lds[DB][MH][0], wsm * 64 + mf * 16 + lr, ks * 4 + lh); \
    }                                                                            \
    if (RB) {                                                                    \
      _Pragma("unroll") for (int nf = 0; nf < 2; ++nf)                           \
        _Pragma("unroll") for (int ks = 0; ks < 2; ++ks)                         \
          bF[NH][nf][ks] = rd_frag(&lds[DB][2 + NH][0], wsn * 32 + nf * 16 + lr, ks * 4 + lh); \
    }                                                                            \
    STAGE_CODE;                                                                  \
    SBAR();                                                                      \
    LGKM0();                                                                     \
    SCHED0();                                                                    \
    __builtin_amdgcn_s_setprio(1);                                               \
    _Pragma("unroll") for (int mf = 0; mf < 4; ++mf)                             \
      _Pragma("unroll") for (int nf = 0; nf < 2; ++nf)                           \
        _Pragma("unroll") for (int ks = 0; ks < 2; ++ks)                         \
          acc[(MH)*4 + mf][(NH)*2 + nf] = __builtin_amdgcn_mfma_f32_16x16x32_bf16( \
              aF[mf][ks], bF[NH][nf][ks], acc[(MH)*4 + mf][(NH)*2 + nf], 0, 0, 0); \
    __builtin_amdgcn_s_setprio(0);                                               \
    GATE_CODE;                                                                   \
    SBAR();                                                                      \
    SCHED0();                                                                    \
  }

__global__ __launch_bounds__(THREADS, 2) void gemm_sc(
    const bf16* __restrict__ A, long sAz, int lda,
    const bf16* __restrict__ B, long sBz, int ldb, int K,
    bf16* __restrict__ p0, long sCz, float scale) {
  __shared__ bf16 lds[2][4][UNIT];   // 128 KiB
  const int tid = threadIdx.x;
  const int wv = tid >> 6, ln = tid & 63;
  const int wsm = wv >> 2, wsn = wv & 3;     // 2M x 4N; wave tile 128x64
  const int lr = ln & 15, lh = ln >> 4;

  // XCD swizzle, decode (z slow, bx, by FAST): each XCD gets one z-half,
  // a 4-wide bx group (A resident), sweeping by.
  const int gx = gridDim.x, gy = gridDim.y;
  const int lin = blockIdx.x + gx * (blockIdx.y + gy * blockIdx.z);
  const int nwg = gx * gy * gridDim.z;
  const int swz = (lin & 7) * (nwg >> 3) + (lin >> 3);
  const int by = swz % gy;
  const int t2 = swz / gy;
  const int bx = t2 % gx;
  const int z  = t2 / gx;

  const int m0 = bx * BM8, n0 = by * BN8;
  const bf16* Ag = A + (long)z * sAz + (long)m0 * lda;
  const bf16* Bg = B + (long)z * sBz + (long)n0 * ldb;
  const int NITER = K / 128;

  stage_unit(Ag,             lda, &lds[0][0][0], tid);
  stage_unit(Bg,             ldb, &lds[0][2][0], tid);
  stage_unit(Ag + 128 * lda, lda, &lds[0][1][0], tid);
  stage_unit(Bg + 128 * ldb, ldb, &lds[0][3][0], tid);
  stage_unit(Ag + 64,        lda, &lds[1][0][0], tid);
  stage_unit(Bg + 64,        ldb, &lds[1][2][0], tid);
  GATE(8);
  SBAR();
  SCHED0();

  f32x4 acc[8][4];
  #pragma unroll
  for (int i = 0; i < 8; ++i)
    #pragma unroll
    for (int j = 0; j < 4; ++j) acc[i][j] = f32x4{0.f, 0.f, 0.f, 0.f};
  bf16x8 aF[4][2], bF[2][2][2];

  for (int it = 0; it < NITER; ++it) {
    const bool nl = (it + 1 < NITER);
    const long ktA = 2L * it + 1, ktB = 2L * it + 2, ktC = 2L * it + 3;
    PHASE(0, 0, 0, 1, 1,
      { stage_unit(Ag + 128 * lda + ktA * 64, lda, &lds[1][1][0], tid); },
      { GATE(6); });
    PHASE(0, 0, 1, 0, 1,
      { stage_unit(Bg + 128 * ldb + ktA * 64, ldb, &lds[1][3][0], tid); },
      { GATE(10); });
    PHASE(0, 1, 0, 1, 0,
      { if (nl) stage_unit(Ag + ktB * 64, lda, &lds[0][0][0], tid); },
      {});
    PHASE(0, 1, 1, 0, 0,
      { if (nl) stage_unit(Bg + ktB * 64, ldb, &lds[0][2][0], tid); },
      { if (nl) { GATE(8); } else { GATE(4); } });
    PHASE(1, 0, 0, 1, 1,
      { if (nl) stage_unit(Ag + 128 * lda + ktB * 64, lda, &lds[0][1][0], tid); },
      { if (nl) { GATE(6); } else { GATE(0); } });
    PHASE(1, 0, 1, 0, 1,
      { if (nl) stage_unit(Bg + 128 * ldb + ktB * 64, ldb, &lds[0][3][0], tid); },
      { GATE(10); });
    PHASE(1, 1, 0, 1, 0,
      { if (nl) stage_unit(Ag + ktC * 64, lda, &lds[1][0][0], tid); },
      {});
    PHASE(1, 1, 1, 0, 0,
      { if (nl) stage_unit(Bg + ktC * 64, ldb, &lds[1][2][0], tid); },
      { GATE(8); });
  }

  #pragma unroll
  for (int mi = 0; mi < 8; ++mi) {
    #pragma unroll
    for (int ni = 0; ni < 4; ++ni) {
      #pragma unroll
      for (int rg = 0; rg < 4; ++rg) {
        const int gm = m0 + (mi >> 2) * 128 + wsm * 64 + (mi & 3) * 16 + lh * 4 + rg;
        const int gn = n0 + (ni >> 1) * 128 + wsn * 32 + (ni & 1) * 16 + lr;
        p0[(size_t)z * sCz + (size_t)gm * 2048 + gn] = (bf16)(acc[mi][ni][rg] * scale);
      }
    }
  }
}

// ===========================================================================
__global__ __launch_bounds__(256) void k_f32_to_bf16(const float* __restrict__ in,
                                                     bf16* __restrict__ out, long n) {
  long i = ((long)blockIdx.x * blockDim.x + threadIdx.x) * 4;
  if (i + 3 < n) {
    float4 v = *(const float4*)(in + i);
    bf16x4 o;
    o[0] = (bf16)v.x; o[1] = (bf16)v.y; o[2] = (bf16)v.z; o[3] = (bf16)v.w;
    *(bf16x4*)(out + i) = o;
  }
}

__global__ __launch_bounds__(256) void k_transpose(const float* __restrict__ in,
                                                   bf16* __restrict__ out, int R, int C) {
  __shared__ float t[32][33];
  int c0 = blockIdx.x * 32, r0 = blockIdx.y * 32;
  int tx = threadIdx.x, ty = threadIdx.y;
  #pragma unroll
  for (int dy = 0; dy < 32; dy += 8)
    t[ty + dy][tx] = in[(size_t)(r0 + ty + dy) * C + c0 + tx];
  __syncthreads();
  #pragma unroll
  for (int dy = 0; dy < 32; dy += 8)
    out[(size_t)(c0 + ty + dy) * R + r0 + tx] = (bf16)t[tx][ty + dy];
}

// bf16 per-batch transpose, 64x64 tiles (128B rows both sides)
__global__ __launch_bounds__(256) void k_transpose_v(const bf16* __restrict__ in,
                                                     bf16* __restrict__ out) {
  __shared__ bf16 t[64][65];
  const int z = blockIdx.z;
  in  += (size_t)z * 2048 * 1024;
  out += (size_t)z * 1024 * 2048;
  int h0 = blockIdx.x * 64, s0 = blockIdx.y * 64;
  int tx = threadIdx.x, ty = threadIdx.y;
  #pragma unroll
  for (int dy = 0; dy < 64; dy += 4)
    t[ty + dy][tx] = in[(size_t)(s0 + ty + dy) * 1024 + h0 + tx];
  __syncthreads();
  #pragma unroll
  for (int dy = 0; dy < 64; dy += 4)
    out[(size_t)(h0 + ty + dy) * 2048 + s0 + tx] = t[tx][ty + dy];
}

__global__ __launch_bounds__(256) void k_softmax(bf16* __restrict__ S) {
  const int row = blockIdx.x;
  bf16* p = S + (size_t)row * 2048;
  const int tid = threadIdx.x;
  bf16x8 vin = *(const bf16x8*)(p + tid * 8);
  float x[8];
  float mx = -1e30f;
  #pragma unroll
  for (int i = 0; i < 8; ++i) { x[i] = (float)vin[i]; mx = fmaxf(mx, x[i]); }
  #pragma unroll
  for (int off = 32; off; off >>= 1) mx = fmaxf(mx, __shfl_down(mx, off));
  __shared__ float redm[4];
  if ((tid & 63) == 0) redm[tid >> 6] = mx;
  __syncthreads();
  mx = fmaxf(fmaxf(redm[0], redm[1]), fmaxf(redm[2], redm[3]));
  float s = 0.f;
  #pragma unroll
  for (int i = 0; i < 8; ++i) { x[i] = __expf(x[i] - mx); s += x[i]; }
  #pragma unroll
  for (int off = 32; off; off >>= 1) s += __shfl_down(s, off);
  __shared__ float reds[4];
  if ((tid & 63) == 0) reds[tid >> 6] = s;
  __syncthreads();
  s = reds[0] + reds[1] + reds[2] + reds[3];
  float inv = 1.0f / s;
  bf16x8 vo;
  #pragma unroll
  for (int i = 0; i < 8; ++i) vo[i] = (bf16)(x[i] * inv);
  *(bf16x8*)(p + tid * 8) = vo;
}

// ---------------------------------------------------------------------------
extern "C" void kernel_launch(void* const* d_in, const int* in_sizes, int n_in,
                              void* d_out, int out_size, void* d_ws, size_t ws_size,
                              hipStream_t stream) {
  const float* x    = (const float*)d_in[0];
  const float* Wqkv = (const float*)d_in[1];
  const float* bqkv = (const float*)d_in[2];
  const float* Wout = (const float*)d_in[3];
  const float* bout = (const float*)d_in[4];
  float* out = (float*)d_out;

  char* w = (char*)d_ws;
  const size_t MB = 1ull << 20;
  bf16* Xb  = (bf16*)(w);             // 16MB; dead after QKV -> reused as VT
  bf16* WqT = (bf16*)(w + 16 * MB);   //  6MB
  bf16* WoT = (bf16*)(w + 22 * MB);   //  2MB
  bf16* Qb  = (bf16*)(w + 24 * MB);   // 16MB
  bf16* Kb  = (bf16*)(w + 40 * MB);   // 16MB
  bf16* Vb  = (bf16*)(w + 56 * MB);   // 16MB
  bf16* Sb  = (bf16*)(w + 72 * MB);   // 32MB (S -> P in place)
  bf16* AO  = (bf16*)(w + 104 * MB);  // 16MB  (total 120MB)
  bf16* VT  = Xb;

  k_f32_to_bf16<<<8192, 256, 0, stream>>>(x, Xb, 8388608L);
  dim3 tb(32, 8);
  k_transpose<<<dim3(96, 32), tb, 0, stream>>>(Wqkv, WqT, 1024, 3072);
  k_transpose<<<dim3(32, 32), tb, 0, stream>>>(Wout, WoT, 1024, 1024);

  // QKV: [8192,1024] x W^T[3072,1024] + bias -> Q,K,V   (768 blocks, 3 rounds)
  gemm_qkv<<<dim3(32, 24), THREADS, 0, stream>>>(
      Xb, 0L, 1024, WqT, 0L, 1024, 1024, Qb, 0L, Kb, Vb, nullptr, bqkv, 1.0f);

  k_transpose_v<<<dim3(16, 32, 4), dim3(64, 4), 0, stream>>>(Vb, VT);

  // scores: per batch Q x K^T * 1/32   (8-phase 256^2, 256 blocks = 1 round)
  gemm_sc<<<dim3(8, 8, 4), THREADS, 0, stream>>>(
      Qb, 2048L * 1024, 1024, Kb, 2048L * 1024, 1024, 1024,
      Sb, 2048L * 2048, 0.03125f);

  k_softmax<<<8192, 256, 0, stream>>>(Sb);

  // PV: per batch P[2048,2048] x VT[1024,2048](B^T) -> AO   (256 blocks)
  gemm_pv<<<dim3(8, 8, 4), THREADS, 0, stream>>>(
      Sb, 2048L * 2048, 2048, VT, 1024L * 2048, 2048, 2048,
      AO, 2048L * 1024, nullptr, nullptr, nullptr, nullptr, 1.0f);

  // out proj + bias -> fp32   (256 blocks)
  gemm_out<<<dim3(32, 8), THREADS, 0, stream>>>(
      AO, 0L, 1024, WoT, 0L, 1024, 1024,
      nullptr, 0L, nullptr, nullptr, out, bout, 1.0f);
}

// Round 5
// 212.775 us; speedup vs baseline: 1.1546x; 1.0217x over previous
//
#include <hip/hip_runtime.h>
#include <cstdint>
#include <cstddef>

// ---------------------------------------------------------------------------
// SelfAttnV2: x[4,2048,1024] fp32 -> QKV proj -> softmax(QK^T/32) V -> out proj
// bf16 MFMA GEMMs, fp32 accum.
//  - QKV / PV / OUT: gemm97 = 128x128 tile, BK=32, 4 waves, 3-slot LDS ring
//    (48 KiB -> 3 blocks/CU), counted vmcnt gate, ONE barrier per K-iter.
//  - SC: 256x256 8-phase template, grid 256 = 1 clean round, z-grouped swizzle.
// ---------------------------------------------------------------------------

typedef __bf16 bf16;
typedef __bf16 bf16x8 __attribute__((ext_vector_type(8)));
typedef __bf16 bf16x4 __attribute__((ext_vector_type(4)));
typedef float  f32x4  __attribute__((ext_vector_type(4)));

#define UNIT 8192   // 256^2 kernel staging unit: 128 rows x 64 k = 16 KiB

__device__ __forceinline__ void gload_lds16(const bf16* g, bf16* l) {
  __builtin_amdgcn_global_load_lds(
      (const __attribute__((address_space(1))) unsigned int*)g,
      (__attribute__((address_space(3))) unsigned int*)l, 16, 0, 0);
}

#define GATE(N)  asm volatile("s_waitcnt vmcnt(" #N ")" ::: "memory")
#define LGKM0()  asm volatile("s_waitcnt lgkmcnt(0)" ::: "memory")
#define SBAR()   __builtin_amdgcn_s_barrier()
#define SCHED0() __builtin_amdgcn_sched_barrier(0)

// ===========================================================================
// gemm97: 128x128, BK=32, 256 threads = 4 waves (2x2), wave tile 64x64.
// LDS ring of 3 K-slots, each slot = A[128][32] + B[128][32] (16 KiB).
// Swizzle for 64B rows: slot' = s ^ ((r>>1)&3)  (uniform banks, write+read same).
// ===========================================================================
#define BK97 32
#define U97  4096   // elements per 128x32 unit

// stage one 128x32 unit: 512 chunks of 16B, 2 per thread (256 threads)
__device__ __forceinline__ void stage97(const bf16* g0, long ld, bf16* u, int tid) {
  const int wv = tid >> 6;
  #pragma unroll
  for (int j = 0; j < 2; ++j) {
    const int c = j * 256 + tid;            // 0..511
    const int r = c >> 2, s = c & 3;
    const int sg = s ^ ((r >> 1) & 3);
    const int cb = j * 256 + (wv << 6);     // wave-uniform chunk base
    gload_lds16(g0 + (long)r * ld + sg * 8, u + (size_t)cb * 8);
  }
}

__device__ __forceinline__ bf16x8 rd97(const bf16* u, int r, int s) {
  return *(const bf16x8*)(u + (size_t)r * 32 + (size_t)((s ^ ((r >> 1) & 3)) * 8));
}

// MODE 0: QKV (+bias -> Q|K|V row-major)  MODE 2: PV -> bf16
// MODE 3: out proj (+bias) -> fp32
template <int MODE>
__device__ __forceinline__ void gemm97_body(
    const bf16* __restrict__ A, long sAz, int lda,
    const bf16* __restrict__ B, long sBz, int ldb, int K,
    bf16* __restrict__ p0, long sCz, bf16* __restrict__ p1, bf16* __restrict__ p2,
    float* __restrict__ fout, const float* __restrict__ bias, float scale) {
  __shared__ bf16 lds[3][2][U97];   // 48 KiB -> 3 blocks/CU
  const int tid = threadIdx.x;
  const int wv = tid >> 6, ln = tid & 63;
  const int wr = wv >> 1, wc = wv & 1;     // 2x2 waves, 64x64 each
  const int lr = ln & 15, lh = ln >> 4;
  const int m0 = blockIdx.x * 128, n0 = blockIdx.y * 128;
  const int z = blockIdx.z;
  const bf16* Ag = A + (long)z * sAz + (long)m0 * lda;
  const bf16* Bg = B + (long)z * sBz + (long)n0 * ldb;
  const int NT = K / BK97;

  // prologue: stage tiles 0,1 (slots 0,1); wait tile 0
  stage97(Ag,        lda, &lds[0][0][0], tid);
  stage97(Bg,        ldb, &lds[0][1][0], tid);
  stage97(Ag + BK97, lda, &lds[1][0][0], tid);
  stage97(Bg + BK97, ldb, &lds[1][1][0], tid);
  GATE(4);
  SCHED0();
  SBAR();

  f32x4 acc[4][4];
  #pragma unroll
  for (int i = 0; i < 4; ++i)
    #pragma unroll
    for (int j = 0; j < 4; ++j) acc[i][j] = f32x4{0.f, 0.f, 0.f, 0.f};

  int rs = 0, ns = 2;
  for (int t = 0; t < NT; ++t) {
    const bf16* Au = &lds[rs][0][0];
    const bf16* Bu = &lds[rs][1][0];
    const bool pf = (t + 2 < NT);
    bf16x8 aF[4], bF[4];
    #pragma unroll
    for (int i = 0; i < 4; ++i) aF[i] = rd97(Au, wr * 64 + i * 16 + lr, lh);
    #pragma unroll
    for (int j = 0; j < 4; ++j) bF[j] = rd97(Bu, wc * 64 + j * 16 + lr, lh);
    if (pf) {
      stage97(Ag + (long)(t + 2) * BK97, lda, &lds[ns][0][0], tid);
      stage97(Bg + (long)(t + 2) * BK97, ldb, &lds[ns][1][0], tid);
    }
    LGKM0();
    SCHED0();
    __builtin_amdgcn_s_setprio(1);
    #pragma unroll
    for (int i = 0; i < 4; ++i)
      #pragma unroll
      for (int j = 0; j < 4; ++j)
        acc[i][j] = __builtin_amdgcn_mfma_f32_16x16x32_bf16(aF[i], bF[j], acc[i][j], 0, 0, 0);
    __builtin_amdgcn_s_setprio(0);
    if (t + 1 < NT) {
      if (pf) { GATE(4); } else { GATE(0); }
      SCHED0();
      SBAR();           // single barrier per iter: all waves' gates passed
    }
    rs = (rs == 2) ? 0 : rs + 1;
    ns = (ns == 2) ? 0 : ns + 1;
  }

  // epilogue: C/D layout col=lane&15, row=(lane>>4)*4+reg
  #pragma unroll
  for (int mf = 0; mf < 4; ++mf) {
    #pragma unroll
    for (int nf = 0; nf < 4; ++nf) {
      #pragma unroll
      for (int rg = 0; rg < 4; ++rg) {
        const int gm = m0 + wr * 64 + mf * 16 + lh * 4 + rg;
        const int gn = n0 + wc * 64 + nf * 16 + lr;
        float v = acc[mf][nf][rg];
        if constexpr (MODE == 0) {
          v += bias[gn];
          if (gn < 1024)       p0[(size_t)gm * 1024 + gn] = (bf16)v;          // Q
          else if (gn < 2048)  p1[(size_t)gm * 1024 + (gn - 1024)] = (bf16)v; // K
          else                 p2[(size_t)gm * 1024 + (gn - 2048)] = (bf16)v; // V
        } else if constexpr (MODE == 2) {
          p0[(size_t)z * sCz + (size_t)gm * 1024 + gn] = (bf16)v;
        } else {
          fout[(size_t)gm * 1024 + gn] = v + bias[gn];
        }
      }
    }
  }
}

#define GEMM_ARGS const bf16* A, long sAz, int lda, const bf16* B, long sBz, int ldb, \
                  int K, bf16* p0, long sCz, bf16* p1, bf16* p2, float* fout,         \
                  const float* bias, float scale
__global__ __launch_bounds__(256, 3) void gemm_qkv(GEMM_ARGS) {
  gemm97_body<0>(A, sAz, lda, B, sBz, ldb, K, p0, sCz, p1, p2, fout, bias, scale);
}
__global__ __launch_bounds__(256, 3) void gemm_pv(GEMM_ARGS) {
  gemm97_body<2>(A, sAz, lda, B, sBz, ldb, K, p0, sCz, p1, p2, fout, bias, scale);
}
__global__ __launch_bounds__(256, 3) void gemm_out(GEMM_ARGS) {
  gemm97_body<3>(A, sAz, lda, B, sBz, ldb, K, p0, sCz, p1, p2, fout, bias, scale);
}

// ===========================================================================
// SC: 256x256 8-phase (unchanged from R4). 512 threads, 8 waves 2M x 4N.
// ===========================================================================
#define THREADS8 512

__device__ __forceinline__ void stage_unit(const bf16* g0, long ld, bf16* ldsu, int tid) {
  const int wv = tid >> 6;
  #pragma unroll
  for (int j = 0; j < 2; ++j) {
    const int c = j * 512 + tid;
    const int r = c >> 3;
    const int sg = (c & 7) ^ (r & 7);
    const int cb = j * 512 + (wv << 6);
    gload_lds16(g0 + (long)r * ld + sg * 8, ldsu + (size_t)cb * 8);
  }
}

__device__ __forceinline__ bf16x8 rd_frag(const bf16* unitb, int r, int s) {
  return *(const bf16x8*)(unitb + (size_t)r * 64 + (size_t)((s ^ (r & 7)) * 8));
}

#define PHASE(DB, MH, NH, RA, RB, STAGE_CODE, GATE_CODE)                         \
  {                                                                              \
    if (RA) {                                                                    \
      _Pragma("unroll") for (int mf = 0; mf < 4; ++mf)                           \
        _Pragma("unroll") for (int ks = 0; ks < 2; ++ks)                         \
          aF[mf][ks] = rd_frag(&lds[DB][MH][0], wsm * 64 + mf * 16 + lr, ks * 4 + lh); \
    }                                                                            \
    if (RB) {                                                                    \
      _Pragma("unroll") for (int nf = 0; nf < 2; ++nf)                           \
        _Pragma("unroll") for (int ks = 0; ks < 2; ++ks)                         \
          bF[NH][nf][ks] = rd_frag(&lds[DB][2 + NH][0], wsn * 32 + nf * 16 + lr, ks * 4 + lh); \
    }                                                                            \
    STAGE_CODE;                                                                  \
    SBAR();                                                                      \
    LGKM0();                                                                     \
    SCHED0();                                                                    \
    __builtin_amdgcn_s_setprio(1);                                               \
    _Pragma("unroll") for (int mf = 0; mf < 4; ++mf)                             \
      _Pragma("unroll") for (int nf = 0; nf < 2; ++nf)                           \
        _Pragma("unroll") for (int ks = 0; ks < 2; ++ks)                         \
          acc[(MH)*4 + mf][(NH)*2 + nf] = __builtin_amdgcn_mfma_f32_16x16x32_bf16( \
              aF[mf][ks], bF[NH][nf][ks], acc[(MH)*4 + mf][(NH)*2 + nf], 0, 0, 0); \
    __builtin_amdgcn_s_setprio(0);                                               \
    GATE_CODE;                                                                   \
    SBAR();                                                                      \
    SCHED0();                                                                    \
  }

__global__ __launch_bounds__(THREADS8, 2) void gemm_sc(
    const bf16* __restrict__ A, long sAz, int lda,
    const bf16* __restrict__ B, long sBz, int ldb, int K,
    bf16* __restrict__ p0, long sCz, float scale) {
  __shared__ bf16 lds[2][4][UNIT];   // 128 KiB
  const int tid = threadIdx.x;
  const int wv = tid >> 6, ln = tid & 63;
  const int wsm = wv >> 2, wsn = wv & 3;
  const int lr = ln & 15, lh = ln >> 4;

  // XCD swizzle, decode (z slow, bx, by FAST)
  const int gx = gridDim.x, gy = gridDim.y;
  const int lin = blockIdx.x + gx * (blockIdx.y + gy * blockIdx.z);
  const int nwg = gx * gy * gridDim.z;
  const int swz = (lin & 7) * (nwg >> 3) + (lin >> 3);
  const int by = swz % gy;
  const int t2 = swz / gy;
  const int bx = t2 % gx;
  const int z  = t2 / gx;

  const int m0 = bx * 256, n0 = by * 256;
  const bf16* Ag = A + (long)z * sAz + (long)m0 * lda;
  const bf16* Bg = B + (long)z * sBz + (long)n0 * ldb;
  const int NITER = K / 128;

  stage_unit(Ag,             lda, &lds[0][0][0], tid);
  stage_unit(Bg,             ldb, &lds[0][2][0], tid);
  stage_unit(Ag + 128 * lda, lda, &lds[0][1][0], tid);
  stage_unit(Bg + 128 * ldb, ldb, &lds[0][3][0], tid);
  stage_unit(Ag + 64,        lda, &lds[1][0][0], tid);
  stage_unit(Bg + 64,        ldb, &lds[1][2][0], tid);
  GATE(8);
  SBAR();
  SCHED0();

  f32x4 acc[8][4];
  #pragma unroll
  for (int i = 0; i < 8; ++i)
    #pragma unroll
    for (int j = 0; j < 4; ++j) acc[i][j] = f32x4{0.f, 0.f, 0.f, 0.f};
  bf16x8 aF[4][2], bF[2][2][2];

  for (int it = 0; it < NITER; ++it) {
    const bool nl = (it + 1 < NITER);
    const long ktA = 2L * it + 1, ktB = 2L * it + 2, ktC = 2L * it + 3;
    PHASE(0, 0, 0, 1, 1,
      { stage_unit(Ag + 128 * lda + ktA * 64, lda, &lds[1][1][0], tid); },
      { GATE(6); });
    PHASE(0, 0, 1, 0, 1,
      { stage_unit(Bg + 128 * ldb + ktA * 64, ldb, &lds[1][3][0], tid); },
      { GATE(10); });
    PHASE(0, 1, 0, 1, 0,
      { if (nl) stage_unit(Ag + ktB * 64, lda, &lds[0][0][0], tid); },
      {});
    PHASE(0, 1, 1, 0, 0,
      { if (nl) stage_unit(Bg + ktB * 64, ldb, &lds[0][2][0], tid); },
      { if (nl) { GATE(8); } else { GATE(4); } });
    PHASE(1, 0, 0, 1, 1,
      { if (nl) stage_unit(Ag + 128 * lda + ktB * 64, lda, &lds[0][1][0], tid); },
      { if (nl) { GATE(6); } else { GATE(0); } });
    PHASE(1, 0, 1, 0, 1,
      { if (nl) stage_unit(Bg + 128 * ldb + ktB * 64, ldb, &lds[0][3][0], tid); },
      { GATE(10); });
    PHASE(1, 1, 0, 1, 0,
      { if (nl) stage_unit(Ag + ktC * 64, lda, &lds[1][0][0], tid); },
      {});
    PHASE(1, 1, 1, 0, 0,
      { if (nl) stage_unit(Bg + ktC * 64, ldb, &lds[1][2][0], tid); },
      { GATE(8); });
  }

  #pragma unroll
  for (int mi = 0; mi < 8; ++mi) {
    #pragma unroll
    for (int ni = 0; ni < 4; ++ni) {
      #pragma unroll
      for (int rg = 0; rg < 4; ++rg) {
        const int gm = m0 + (mi >> 2) * 128 + wsm * 64 + (mi & 3) * 16 + lh * 4 + rg;
        const int gn = n0 + (ni >> 1) * 128 + wsn * 32 + (ni & 1) * 16 + lr;
        p0[(size_t)z * sCz + (size_t)gm * 2048 + gn] = (bf16)(acc[mi][ni][rg] * scale);
      }
    }
  }
}

// ===========================================================================
__global__ __launch_bounds__(256) void k_f32_to_bf16(const float* __restrict__ in,
                                                     bf16* __restrict__ out, long n) {
  long i = ((long)blockIdx.x * blockDim.x + threadIdx.x) * 4;
  if (i + 3 < n) {
    float4 v = *(const float4*)(in + i);
    bf16x4 o;
    o[0] = (bf16)v.x; o[1] = (bf16)v.y; o[2] = (bf16)v.z; o[3] = (bf16)v.w;
    *(bf16x4*)(out + i) = o;
  }
}

__global__ __launch_bounds__(256) void k_transpose(const float* __restrict__ in,
                                                   bf16* __restrict__ out, int R, int C) {
  __shared__ float t[32][33];
  int c0 = blockIdx.x * 32, r0 = blockIdx.y * 32;
  int tx = threadIdx.x, ty = threadIdx.y;
  #pragma unroll
  for (int dy = 0; dy < 32; dy += 8)
    t[ty + dy][tx] = in[(size_t)(r0 + ty + dy) * C + c0 + tx];
  __syncthreads();
  #pragma unroll
  for (int dy = 0; dy < 32; dy += 8)
    out[(size_t)(c0 + ty + dy) * R + r0 + tx] = (bf16)t[tx][ty + dy];
}

__global__ __launch_bounds__(256) void k_transpose_v(const bf16* __restrict__ in,
                                                     bf16* __restrict__ out) {
  __shared__ bf16 t[64][65];
  const int z = blockIdx.z;
  in  += (size_t)z * 2048 * 1024;
  out += (size_t)z * 1024 * 2048;
  int h0 = blockIdx.x * 64, s0 = blockIdx.y * 64;
  int tx = threadIdx.x, ty = threadIdx.y;
  #pragma unroll
  for (int dy = 0; dy < 64; dy += 4)
    t[ty + dy][tx] = in[(size_t)(s0 + ty + dy) * 1024 + h0 + tx];
  __syncthreads();
  #pragma unroll
  for (int dy = 0; dy < 64; dy += 4)
    out[(size_t)(h0 + ty + dy) * 2048 + s0 + tx] = t[tx][ty + dy];
}

__global__ __launch_bounds__(256) void k_softmax(bf16* __restrict__ S) {
  const int row = blockIdx.x;
  bf16* p = S + (size_t)row * 2048;
  const int tid = threadIdx.x;
  bf16x8 vin = *(const bf16x8*)(p + tid * 8);
  float x[8];
  float mx = -1e30f;
  #pragma unroll
  for (int i = 0; i < 8; ++i) { x[i] = (float)vin[i]; mx = fmaxf(mx, x[i]); }
  #pragma unroll
  for (int off = 32; off; off >>= 1) mx = fmaxf(mx, __shfl_down(mx, off));
  __shared__ float redm[4];
  if ((tid & 63) == 0) redm[tid >> 6] = mx;
  __syncthreads();
  mx = fmaxf(fmaxf(redm[0], redm[1]), fmaxf(redm[2], redm[3]));
  float s = 0.f;
  #pragma unroll
  for (int i = 0; i < 8; ++i) { x[i] = __expf(x[i] - mx); s += x[i]; }
  #pragma unroll
  for (int off = 32; off; off >>= 1) s += __shfl_down(s, off);
  __shared__ float reds[4];
  if ((tid & 63) == 0) reds[tid >> 6] = s;
  __syncthreads();
  s = reds[0] + reds[1] + reds[2] + reds[3];
  float inv = 1.0f / s;
  bf16x8 vo;
  #pragma unroll
  for (int i = 0; i < 8; ++i) vo[i] = (bf16)(x[i] * inv);
  *(bf16x8*)(p + tid * 8) = vo;
}

// ---------------------------------------------------------------------------
extern "C" void kernel_launch(void* const* d_in, const int* in_sizes, int n_in,
                              void* d_out, int out_size, void* d_ws, size_t ws_size,
                              hipStream_t stream) {
  const float* x    = (const float*)d_in[0];
  const float* Wqkv = (const float*)d_in[1];
  const float* bqkv = (const float*)d_in[2];
  const float* Wout = (const float*)d_in[3];
  const float* bout = (const float*)d_in[4];
  float* out = (float*)d_out;

  char* w = (char*)d_ws;
  const size_t MB = 1ull << 20;
  bf16* Xb  = (bf16*)(w);             // 16MB; dead after QKV -> reused as VT
  bf16* WqT = (bf16*)(w + 16 * MB);   //  6MB
  bf16* WoT = (bf16*)(w + 22 * MB);   //  2MB
  bf16* Qb  = (bf16*)(w + 24 * MB);   // 16MB
  bf16* Kb  = (bf16*)(w + 40 * MB);   // 16MB
  bf16* Vb  = (bf16*)(w + 56 * MB);   // 16MB
  bf16* Sb  = (bf16*)(w + 72 * MB);   // 32MB (S -> P in place)
  bf16* AO  = (bf16*)(w + 104 * MB);  // 16MB  (total 120MB)
  bf16* VT  = Xb;

  k_f32_to_bf16<<<8192, 256, 0, stream>>>(x, Xb, 8388608L);
  dim3 tb(32, 8);
  k_transpose<<<dim3(96, 32), tb, 0, stream>>>(Wqkv, WqT, 1024, 3072);
  k_transpose<<<dim3(32, 32), tb, 0, stream>>>(Wout, WoT, 1024, 1024);

  // QKV: [8192,1024] x W^T[3072,1024] + bias -> Q,K,V   (1536 blocks)
  gemm_qkv<<<dim3(64, 24), 256, 0, stream>>>(
      Xb, 0L, 1024, WqT, 0L, 1024, 1024, Qb, 0L, Kb, Vb, nullptr, bqkv, 1.0f);

  k_transpose_v<<<dim3(16, 32, 4), dim3(64, 4), 0, stream>>>(Vb, VT);

  // scores: per batch Q x K^T * 1/32   (8-phase 256^2, 256 blocks = 1 round)
  gemm_sc<<<dim3(8, 8, 4), THREADS8, 0, stream>>>(
      Qb, 2048L * 1024, 1024, Kb, 2048L * 1024, 1024, 1024,
      Sb, 2048L * 2048, 0.03125f);

  k_softmax<<<8192, 256, 0, stream>>>(Sb);

  // PV: per batch P[2048,2048] x VT[1024,2048](B^T) -> AO   (512 blocks)
  gemm_pv<<<dim3(16, 8, 4), 256, 0, stream>>>(
      Sb, 2048L * 2048, 2048, VT, 1024L * 2048, 2048, 2048,
      AO, 2048L * 1024, nullptr, nullptr, nullptr, nullptr, 1.0f);

  // out proj + bias -> fp32   (512 blocks)
  gemm_out<<<dim3(64, 8), 256, 0, stream>>>(
      AO, 0L, 1024, WoT, 0L, 1024, 1024,
      nullptr, 0L, nullptr, nullptr, out, bout, 1.0f);
}

// Round 6
// 209.901 us; speedup vs baseline: 1.1704x; 1.0137x over previous
//
#include <hip/hip_runtime.h>
#include <cstdint>
#include <cstddef>

// ---------------------------------------------------------------------------
// SelfAttnV2: x[4,2048,1024] fp32 -> QKV proj -> softmax(QK^T/32) V -> out proj
// bf16 MFMA GEMMs, fp32 accum.
// Pipeline (reassociated): QKV -> SC -> softmax -> VWT = Wo^T x V^T -> PVW = P x VWT
//   (P.V).Wo == P.(V.Wo): same FLOPs, kills V-transpose kernel + AO roundtrip.
//  - QKV / VWT / PVW: gemm97 = 128x128, BK=32, 4 waves, 3-slot LDS ring
//    (48 KiB -> 3 blocks/CU), counted vmcnt gate, ONE barrier per K-iter.
//  - SC: 256x256 8-phase template, grid 256 = 1 clean round, z-grouped swizzle.
// ---------------------------------------------------------------------------

typedef __bf16 bf16;
typedef __bf16 bf16x8 __attribute__((ext_vector_type(8)));
typedef __bf16 bf16x4 __attribute__((ext_vector_type(4)));
typedef float  f32x4  __attribute__((ext_vector_type(4)));

#define UNIT 8192   // 256^2 kernel staging unit: 128 rows x 64 k = 16 KiB

__device__ __forceinline__ void gload_lds16(const bf16* g, bf16* l) {
  __builtin_amdgcn_global_load_lds(
      (const __attribute__((address_space(1))) unsigned int*)g,
      (__attribute__((address_space(3))) unsigned int*)l, 16, 0, 0);
}

#define GATE(N)  asm volatile("s_waitcnt vmcnt(" #N ")" ::: "memory")
#define LGKM0()  asm volatile("s_waitcnt lgkmcnt(0)" ::: "memory")
#define SBAR()   __builtin_amdgcn_s_barrier()
#define SCHED0() __builtin_amdgcn_sched_barrier(0)

// ===========================================================================
// gemm97: 128x128, BK=32, 256 threads = 4 waves (2x2), wave tile 64x64.
// LDS ring of 3 K-slots, each slot = A[128][32] + B[128][32] (16 KiB).
// Swizzle for 64B rows: slot' = s ^ ((r>>1)&3).
// ===========================================================================
#define BK97 32
#define U97  4096   // elements per 128x32 unit

__device__ __forceinline__ void stage97(const bf16* g0, long ld, bf16* u, int tid) {
  const int wv = tid >> 6;
  #pragma unroll
  for (int j = 0; j < 2; ++j) {
    const int c = j * 256 + tid;            // 0..511
    const int r = c >> 2, s = c & 3;
    const int sg = s ^ ((r >> 1) & 3);
    const int cb = j * 256 + (wv << 6);     // wave-uniform chunk base
    gload_lds16(g0 + (long)r * ld + sg * 8, u + (size_t)cb * 8);
  }
}

__device__ __forceinline__ bf16x8 rd97(const bf16* u, int r, int s) {
  return *(const bf16x8*)(u + (size_t)r * 32 + (size_t)((s ^ ((r >> 1) & 3)) * 8));
}

// MODE 0: QKV (+bias -> Q|K|V row-major, ldc=1024)
// MODE 2: bf16 store at ldc
// MODE 3: fp32 store (+bias) at ldc
template <int MODE>
__device__ __forceinline__ void gemm97_body(
    const bf16* __restrict__ A, long sAz, int lda,
    const bf16* __restrict__ B, long sBz, int ldb, int K,
    bf16* __restrict__ p0, long sCz, int ldc,
    bf16* __restrict__ p1, bf16* __restrict__ p2,
    float* __restrict__ fout, long sFz,
    const float* __restrict__ bias, float scale) {
  __shared__ bf16 lds[3][2][U97];   // 48 KiB -> 3 blocks/CU
  const int tid = threadIdx.x;
  const int wv = tid >> 6, ln = tid & 63;
  const int wr = wv >> 1, wc = wv & 1;     // 2x2 waves, 64x64 each
  const int lr = ln & 15, lh = ln >> 4;
  const int m0 = blockIdx.x * 128, n0 = blockIdx.y * 128;
  const int z = blockIdx.z;
  const bf16* Ag = A + (long)z * sAz + (long)m0 * lda;
  const bf16* Bg = B + (long)z * sBz + (long)n0 * ldb;
  const int NT = K / BK97;

  stage97(Ag,        lda, &lds[0][0][0], tid);
  stage97(Bg,        ldb, &lds[0][1][0], tid);
  stage97(Ag + BK97, lda, &lds[1][0][0], tid);
  stage97(Bg + BK97, ldb, &lds[1][1][0], tid);
  GATE(4);
  SCHED0();
  SBAR();

  f32x4 acc[4][4];
  #pragma unroll
  for (int i = 0; i < 4; ++i)
    #pragma unroll
    for (int j = 0; j < 4; ++j) acc[i][j] = f32x4{0.f, 0.f, 0.f, 0.f};

  int rs = 0, ns = 2;
  for (int t = 0; t < NT; ++t) {
    const bf16* Au = &lds[rs][0][0];
    const bf16* Bu = &lds[rs][1][0];
    const bool pf = (t + 2 < NT);
    bf16x8 aF[4], bF[4];
    #pragma unroll
    for (int i = 0; i < 4; ++i) aF[i] = rd97(Au, wr * 64 + i * 16 + lr, lh);
    #pragma unroll
    for (int j = 0; j < 4; ++j) bF[j] = rd97(Bu, wc * 64 + j * 16 + lr, lh);
    if (pf) {
      stage97(Ag + (long)(t + 2) * BK97, lda, &lds[ns][0][0], tid);
      stage97(Bg + (long)(t + 2) * BK97, ldb, &lds[ns][1][0], tid);
    }
    LGKM0();
    SCHED0();
    __builtin_amdgcn_s_setprio(1);
    #pragma unroll
    for (int i = 0; i < 4; ++i)
      #pragma unroll
      for (int j = 0; j < 4; ++j)
        acc[i][j] = __builtin_amdgcn_mfma_f32_16x16x32_bf16(aF[i], bF[j], acc[i][j], 0, 0, 0);
    __builtin_amdgcn_s_setprio(0);
    if (t + 1 < NT) {
      if (pf) { GATE(4); } else { GATE(0); }
      SCHED0();
      SBAR();
    }
    rs = (rs == 2) ? 0 : rs + 1;
    ns = (ns == 2) ? 0 : ns + 1;
  }

  // epilogue: C/D layout col=lane&15, row=(lane>>4)*4+reg
  #pragma unroll
  for (int mf = 0; mf < 4; ++mf) {
    #pragma unroll
    for (int nf = 0; nf < 4; ++nf) {
      #pragma unroll
      for (int rg = 0; rg < 4; ++rg) {
        const int gm = m0 + wr * 64 + mf * 16 + lh * 4 + rg;
        const int gn = n0 + wc * 64 + nf * 16 + lr;
        float v = acc[mf][nf][rg];
        if constexpr (MODE == 0) {
          v += bias[gn];
          if (gn < 1024)       p0[(size_t)gm * 1024 + gn] = (bf16)v;          // Q
          else if (gn < 2048)  p1[(size_t)gm * 1024 + (gn - 1024)] = (bf16)v; // K
          else                 p2[(size_t)gm * 1024 + (gn - 2048)] = (bf16)v; // V
        } else if constexpr (MODE == 2) {
          p0[(size_t)z * sCz + (size_t)gm * ldc + gn] = (bf16)(v * scale);
        } else {
          fout[(size_t)z * sFz + (size_t)gm * ldc + gn] = v + bias[gn];
        }
      }
    }
  }
}

#define GEMM_ARGS const bf16* A, long sAz, int lda, const bf16* B, long sBz, int ldb, \
                  int K, bf16* p0, long sCz, int ldc, bf16* p1, bf16* p2,             \
                  float* fout, long sFz, const float* bias, float scale
__global__ __launch_bounds__(256, 3) void gemm_qkv(GEMM_ARGS) {
  gemm97_body<0>(A, sAz, lda, B, sBz, ldb, K, p0, sCz, ldc, p1, p2, fout, sFz, bias, scale);
}
__global__ __launch_bounds__(256, 3) void gemm_vwt(GEMM_ARGS) {
  gemm97_body<2>(A, sAz, lda, B, sBz, ldb, K, p0, sCz, ldc, p1, p2, fout, sFz, bias, scale);
}
__global__ __launch_bounds__(256, 3) void gemm_pvw(GEMM_ARGS) {
  gemm97_body<3>(A, sAz, lda, B, sBz, ldb, K, p0, sCz, ldc, p1, p2, fout, sFz, bias, scale);
}

// ===========================================================================
// SC: 256x256 8-phase (unchanged, measured-good). 512 threads, 8 waves 2M x 4N.
// ===========================================================================
#define THREADS8 512

__device__ __forceinline__ void stage_unit(const bf16* g0, long ld, bf16* ldsu, int tid) {
  const int wv = tid >> 6;
  #pragma unroll
  for (int j = 0; j < 2; ++j) {
    const int c = j * 512 + tid;
    const int r = c >> 3;
    const int sg = (c & 7) ^ (r & 7);
    const int cb = j * 512 + (wv << 6);
    gload_lds16(g0 + (long)r * ld + sg * 8, ldsu + (size_t)cb * 8);
  }
}

__device__ __forceinline__ bf16x8 rd_frag(const bf16* unitb, int r, int s) {
  return *(const bf16x8*)(unitb + (size_t)r * 64 + (size_t)((s ^ (r & 7)) * 8));
}

#define PHASE(DB, MH, NH, RA, RB, STAGE_CODE, GATE_CODE)                         \
  {                                                                              \
    if (RA) {                                                                    \
      _Pragma("unroll") for (int mf = 0; mf < 4; ++mf)                           \
        _Pragma("unroll") for (int ks = 0; ks < 2; ++ks)                         \
          aF[mf][ks] = rd_frag(&lds[DB][MH][0], wsm * 64 + mf * 16 + lr, ks * 4 + lh); \
    }                                                                            \
    if (RB) {                                                                    \
      _Pragma("unroll") for (int nf = 0; nf < 2; ++nf)                           \
        _Pragma("unroll") for (int ks = 0; ks < 2; ++ks)                         \
          bF[NH][nf][ks] = rd_frag(&lds[DB][2 + NH][0], wsn * 32 + nf * 16 + lr, ks * 4 + lh); \
    }                                                                            \
    STAGE_CODE;                                                                  \
    SBAR();                                                                      \
    LGKM0();                                                                     \
    SCHED0();                                                                    \
    __builtin_amdgcn_s_setprio(1);                                               \
    _Pragma("unroll") for (int mf = 0; mf < 4; ++mf)                             \
      _Pragma("unroll") for (int nf = 0; nf < 2; ++nf)                           \
        _Pragma("unroll") for (int ks = 0; ks < 2; ++ks)                         \
          acc[(MH)*4 + mf][(NH)*2 + nf] = __builtin_amdgcn_mfma_f32_16x16x32_bf16( \
              aF[mf][ks], bF[NH][nf][ks], acc[(MH)*4 + mf][(NH)*2 + nf], 0, 0, 0); \
    __builtin_amdgcn_s_setprio(0);                                               \
    GATE_CODE;                                                                   \
    SBAR();                                                                      \
    SCHED0();                                                                    \
  }

__global__ __launch_bounds__(THREADS8, 2) void gemm_sc(
    const bf16* __restrict__ A, long sAz, int lda,
    const bf16* __restrict__ B, long sBz, int ldb, int K,
    bf16* __restrict__ p0, long sCz, float scale) {
  __shared__ bf16 lds[2][4][UNIT];   // 128 KiB
  const int tid = threadIdx.x;
  const int wv = tid >> 6, ln = tid & 63;
  const int wsm = wv >> 2, wsn = wv & 3;
  const int lr = ln & 15, lh = ln >> 4;

  const int gx = gridDim.x, gy = gridDim.y;
  const int lin = blockIdx.x + gx * (blockIdx.y + gy * blockIdx.z);
  const int nwg = gx * gy * gridDim.z;
  const int swz = (lin & 7) * (nwg >> 3) + (lin >> 3);
  const int by = swz % gy;
  const int t2 = swz / gy;
  const int bx = t2 % gx;
  const int z  = t2 / gx;

  const int m0 = bx * 256, n0 = by * 256;
  const bf16* Ag = A + (long)z * sAz + (long)m0 * lda;
  const bf16* Bg = B + (long)z * sBz + (long)n0 * ldb;
  const int NITER = K / 128;

  stage_unit(Ag,             lda, &lds[0][0][0], tid);
  stage_unit(Bg,             ldb, &lds[0][2][0], tid);
  stage_unit(Ag + 128 * lda, lda, &lds[0][1][0], tid);
  stage_unit(Bg + 128 * ldb, ldb, &lds[0][3][0], tid);
  stage_unit(Ag + 64,        lda, &lds[1][0][0], tid);
  stage_unit(Bg + 64,        ldb, &lds[1][2][0], tid);
  GATE(8);
  SBAR();
  SCHED0();

  f32x4 acc[8][4];
  #pragma unroll
  for (int i = 0; i < 8; ++i)
    #pragma unroll
    for (int j = 0; j < 4; ++j) acc[i][j] = f32x4{0.f, 0.f, 0.f, 0.f};
  bf16x8 aF[4][2], bF[2][2][2];

  for (int it = 0; it < NITER; ++it) {
    const bool nl = (it + 1 < NITER);
    const long ktA = 2L * it + 1, ktB = 2L * it + 2, ktC = 2L * it + 3;
    PHASE(0, 0, 0, 1, 1,
      { stage_unit(Ag + 128 * lda + ktA * 64, lda, &lds[1][1][0], tid); },
      { GATE(6); });
    PHASE(0, 0, 1, 0, 1,
      { stage_unit(Bg + 128 * ldb + ktA * 64, ldb, &lds[1][3][0], tid); },
      { GATE(10); });
    PHASE(0, 1, 0, 1, 0,
      { if (nl) stage_unit(Ag + ktB * 64, lda, &lds[0][0][0], tid); },
      {});
    PHASE(0, 1, 1, 0, 0,
      { if (nl) stage_unit(Bg + ktB * 64, ldb, &lds[0][2][0], tid); },
      { if (nl) { GATE(8); } else { GATE(4); } });
    PHASE(1, 0, 0, 1, 1,
      { if (nl) stage_unit(Ag + 128 * lda + ktB * 64, lda, &lds[0][1][0], tid); },
      { if (nl) { GATE(6); } else { GATE(0); } });
    PHASE(1, 0, 1, 0, 1,
      { if (nl) stage_unit(Bg + 128 * ldb + ktB * 64, ldb, &lds[0][3][0], tid); },
      { GATE(10); });
    PHASE(1, 1, 0, 1, 0,
      { if (nl) stage_unit(Ag + ktC * 64, lda, &lds[1][0][0], tid); },
      {});
    PHASE(1, 1, 1, 0, 0,
      { if (nl) stage_unit(Bg + ktC * 64, ldb, &lds[1][2][0], tid); },
      { GATE(8); });
  }

  #pragma unroll
  for (int mi = 0; mi < 8; ++mi) {
    #pragma unroll
    for (int ni = 0; ni < 4; ++ni) {
      #pragma unroll
      for (int rg = 0; rg < 4; ++rg) {
        const int gm = m0 + (mi >> 2) * 128 + wsm * 64 + (mi & 3) * 16 + lh * 4 + rg;
        const int gn = n0 + (ni >> 1) * 128 + wsn * 32 + (ni & 1) * 16 + lr;
        p0[(size_t)z * sCz + (size_t)gm * 2048 + gn] = (bf16)(acc[mi][ni][rg] * scale);
      }
    }
  }
}

// ===========================================================================
__global__ __launch_bounds__(256) void k_f32_to_bf16(const float* __restrict__ in,
                                                     bf16* __restrict__ out, long n) {
  long i = ((long)blockIdx.x * blockDim.x + threadIdx.x) * 4;
  if (i + 3 < n) {
    float4 v = *(const float4*)(in + i);
    bf16x4 o;
    o[0] = (bf16)v.x; o[1] = (bf16)v.y; o[2] = (bf16)v.z; o[3] = (bf16)v.w;
    *(bf16x4*)(out + i) = o;
  }
}

__global__ __launch_bounds__(256) void k_transpose(const float* __restrict__ in,
                                                   bf16* __restrict__ out, int R, int C) {
  __shared__ float t[32][33];
  int c0 = blockIdx.x * 32, r0 = blockIdx.y * 32;
  int tx = threadIdx.x, ty = threadIdx.y;
  #pragma unroll
  for (int dy = 0; dy < 32; dy += 8)
    t[ty + dy][tx] = in[(size_t)(r0 + ty + dy) * C + c0 + tx];
  __syncthreads();
  #pragma unroll
  for (int dy = 0; dy < 32; dy += 8)
    out[(size_t)(c0 + ty + dy) * R + r0 + tx] = (bf16)t[tx][ty + dy];
}

__global__ __launch_bounds__(256) void k_softmax(bf16* __restrict__ S) {
  const int row = blockIdx.x;
  bf16* p = S + (size_t)row * 2048;
  const int tid = threadIdx.x;
  bf16x8 vin = *(const bf16x8*)(p + tid * 8);
  float x[8];
  float mx = -1e30f;
  #pragma unroll
  for (int i = 0; i < 8; ++i) { x[i] = (float)vin[i]; mx = fmaxf(mx, x[i]); }
  #pragma unroll
  for (int off = 32; off; off >>= 1) mx = fmaxf(mx, __shfl_down(mx, off));
  __shared__ float redm[4];
  if ((tid & 63) == 0) redm[tid >> 6] = mx;
  __syncthreads();
  mx = fmaxf(fmaxf(redm[0], redm[1]), fmaxf(redm[2], redm[3]));
  float s = 0.f;
  #pragma unroll
  for (int i = 0; i < 8; ++i) { x[i] = __expf(x[i] - mx); s += x[i]; }
  #pragma unroll
  for (int off = 32; off; off >>= 1) s += __shfl_down(s, off);
  __shared__ float reds[4];
  if ((tid & 63) == 0) reds[tid >> 6] = s;
  __syncthreads();
  s = reds[0] + reds[1] + reds[2] + reds[3];
  float inv = 1.0f / s;
  bf16x8 vo;
  #pragma unroll
  for (int i = 0; i < 8; ++i) vo[i] = (bf16)(x[i] * inv);
  *(bf16x8*)(p + tid * 8) = vo;
}

// ---------------------------------------------------------------------------
extern "C" void kernel_launch(void* const* d_in, const int* in_sizes, int n_in,
                              void* d_out, int out_size, void* d_ws, size_t ws_size,
                              hipStream_t stream) {
  const float* x    = (const float*)d_in[0];
  const float* Wqkv = (const float*)d_in[1];
  const float* bqkv = (const float*)d_in[2];
  const float* Wout = (const float*)d_in[3];
  const float* bout = (const float*)d_in[4];
  float* out = (float*)d_out;

  char* w = (char*)d_ws;
  const size_t MB = 1ull << 20;
  bf16* Xb  = (bf16*)(w);             // 16MB
  bf16* WqT = (bf16*)(w + 16 * MB);   //  6MB
  bf16* WoT = (bf16*)(w + 22 * MB);   //  2MB
  bf16* Qb  = (bf16*)(w + 24 * MB);   // 16MB
  bf16* Kb  = (bf16*)(w + 40 * MB);   // 16MB
  bf16* Vb  = (bf16*)(w + 56 * MB);   // 16MB
  bf16* Sb  = (bf16*)(w + 72 * MB);   // 32MB (S -> P in place)
  bf16* VWT = (bf16*)(w + 104 * MB);  // 16MB [4][1024][2048]  (total 120MB)

  k_f32_to_bf16<<<8192, 256, 0, stream>>>(x, Xb, 8388608L);
  dim3 tb(32, 8);
  k_transpose<<<dim3(96, 32), tb, 0, stream>>>(Wqkv, WqT, 1024, 3072);
  k_transpose<<<dim3(32, 32), tb, 0, stream>>>(Wout, WoT, 1024, 1024);

  // QKV: [8192,1024] x W^T[3072,1024] + bias -> Q,K,V   (1536 blocks)
  gemm_qkv<<<dim3(64, 24), 256, 0, stream>>>(
      Xb, 0L, 1024, WqT, 0L, 1024, 1024,
      Qb, 0L, 1024, Kb, Vb, nullptr, 0L, bqkv, 1.0f);

  // VWT[z][d][s] = sum_h WoT[d][h] * V[z][s][h]   (512 blocks; V row-major!)
  gemm_vwt<<<dim3(8, 16, 4), 256, 0, stream>>>(
      WoT, 0L, 1024, Vb, 2048L * 1024, 1024, 1024,
      VWT, 1024L * 2048, 2048, nullptr, nullptr, nullptr, 0L, nullptr, 1.0f);

  // scores: per batch Q x K^T * 1/32   (8-phase 256^2, 256 blocks = 1 round)
  gemm_sc<<<dim3(8, 8, 4), THREADS8, 0, stream>>>(
      Qb, 2048L * 1024, 1024, Kb, 2048L * 1024, 1024, 1024,
      Sb, 2048L * 2048, 0.03125f);

  k_softmax<<<8192, 256, 0, stream>>>(Sb);

  // out[z][q][d] = sum_s P[z][q][s] * VWT[z][d][s] + bout[d]   (512 blocks, fp32)
  gemm_pvw<<<dim3(16, 8, 4), 256, 0, stream>>>(
      Sb, 2048L * 2048, 2048, VWT, 1024L * 2048, 2048, 2048,
      nullptr, 0L, 1024, nullptr, nullptr, out, 2048L * 1024, bout, 1.0f);
}